// Round 3
// baseline (1875.375 us; speedup 1.0000x reference)
//
#include <hip/hip_runtime.h>
#include <hip/hip_fp16.h>

#define H 4096

// ---------------------------------------------------------------------------
// Single persistent kernel, 768 blocks x 256 thr (3 blocks/CU co-resident via
// __launch_bounds__(256,3)), hand-rolled grid barrier between phases.
// ws layout: L16[3*H*H] | R16[3*H*H] (fp16, l=3 is identity -> skipped) |
// f slots (H floats each):
//   atomic acc (zeroed P0): 0-2 xL | 3-5 hL | 6-8 hR | 9-11 rR | 12-14 z1R |
//     15-17 rhR | 18-20 omzR | 21-23 z2hR | 24-26 htL | 27-29 zhL | 30 scores
//   cands: 31-34 rh | 35-38 omz | 39-42 z2h | 43-46 ht | 47-50 zh | 51-54 hn
//   mixes: 57 rh | 58 omz | 59 z2h | 60 ht | 61 zh
//   62: barrier state (ints, memset to 0 on host each call)
// ---------------------------------------------------------------------------

__device__ __forceinline__ float sigmoidf_(float x) {
  return 1.0f / (1.0f + expf(-x));
}

__device__ __forceinline__ void soft4(const float* sc, float* w) {
  float s0 = sc[0], s1 = sc[1], s2 = sc[2], s3 = sc[3];
  float mx = fmaxf(fmaxf(s0, s1), fmaxf(s2, s3));
  float e0 = expf(s0 - mx), e1 = expf(s1 - mx);
  float e2 = expf(s2 - mx), e3 = expf(s3 - mx);
  float inv = 1.0f / (e0 + e1 + e2 + e3);
  w[0] = e0 * inv; w[1] = e1 * inv; w[2] = e2 * inv; w[3] = e3 * inv;
}

__device__ __forceinline__ void idxmargin(const float* sc, float* dout, int os) {
  float s[4] = {sc[0], sc[1], sc[2], sc[3]};
  int idx = 0; float mx = s[0];
  for (int q = 1; q < 4; ++q) if (s[q] > mx) { mx = s[q]; idx = q; }
  float second = -1e30f;
  for (int q = 0; q < 4; ++q) if (q != idx && s[q] > second) second = s[q];
  dout[H + 3 + os] = (float)idx;
  dout[H + 9 + os] = mx - second;
}

// two-level grid barrier: 12 groups of 64 blocks -> root -> generation bump.
// bar[0]=gen, bar[16]=root, bar[32+g*16]=group counters (line-padded).
__device__ __forceinline__ void gridbar(int* bar) {
  __syncthreads();          // drains vmcnt: all block stores acked by L2
  __threadfence();          // release: L2 writeback to coherence point
  if (threadIdx.x == 0) {
    int* gen  = bar;
    int* root = bar + 16;
    int* gcnt = bar + 32 + (blockIdx.x >> 6) * 16;
    int g = __hip_atomic_load(gen, __ATOMIC_RELAXED, __HIP_MEMORY_SCOPE_AGENT);
    bool done = false;
    if (atomicAdd(gcnt, 1) == 63) {
      atomicExch(gcnt, 0);
      if (atomicAdd(root, 1) == 11) {
        atomicExch(root, 0);
        atomicAdd(gen, 1);
        done = true;
      }
    }
    if (!done) {
      while (__hip_atomic_load(gen, __ATOMIC_RELAXED,
                               __HIP_MEMORY_SCOPE_AGENT) == g)
        __builtin_amdgcn_s_sleep(4);
    }
  }
  __syncthreads();
  __threadfence();          // acquire: invalidate L1/L2 before fresh reads
}

// block-level reduce of NW partials -> atomicAdd into scdst[0..NW)
template<int NW>
__device__ __forceinline__ void reduce_atomic(float* vals, float* scdst, int tid) {
  __shared__ float red[4][12];
  const int lane = tid & 63, wv = tid >> 6;
#pragma unroll
  for (int j = 0; j < NW; ++j) {
    float v = vals[j];
#pragma unroll
    for (int off = 32; off > 0; off >>= 1) v += __shfl_down(v, off);
    if (lane == 0) red[wv][j] = v;
  }
  __syncthreads();
  if (tid < NW)
    atomicAdd(scdst + tid, red[0][tid] + red[1][tid] + red[2][tid] + red[3][tid]);
}

// f32 gemv + fp16 convert. task in [0,384): hc(32,128rows) x kt(4,1024cols) x l(3)
template<int NV>
__device__ void phase_gemv32(const float* __restrict__ M,
                             const float* __restrict__ V0,
                             const float* __restrict__ V1,
                             float* __restrict__ fout,
                             __half* __restrict__ M16, int task, float* smem) {
  const int hc = task & 31, kt = (task >> 5) & 3, l = task >> 7;
  const int tid = threadIdx.x;
  const int k0 = kt * 1024 + tid * 4;
  const int h0 = hc * 128;
  if (tid < 128) smem[tid] = V0[h0 + tid];
  else if (NV > 1) smem[tid] = V1[h0 + tid - 128];
  __syncthreads();

  const size_t base = ((size_t)l * H + h0) * H + k0;
  const float* Mp = M + base;
  __half* M16p = M16 + base;

  float acc[NV][4];
#pragma unroll
  for (int v = 0; v < NV; ++v)
#pragma unroll
    for (int j = 0; j < 4; ++j) acc[v][j] = 0.0f;

#pragma unroll 4
  for (int hh = 0; hh < 128; ++hh) {
    float4 m = *reinterpret_cast<const float4*>(Mp + (size_t)hh * H);
    __half t[4] = {__float2half(m.x), __float2half(m.y),
                   __float2half(m.z), __float2half(m.w)};
    *reinterpret_cast<uint2*>(M16p + (size_t)hh * H) =
        *reinterpret_cast<const uint2*>(t);
#pragma unroll
    for (int v = 0; v < NV; ++v) {
      const float s = smem[v * 128 + hh];
      acc[v][0] = fmaf(s, m.x, acc[v][0]);
      acc[v][1] = fmaf(s, m.y, acc[v][1]);
      acc[v][2] = fmaf(s, m.z, acc[v][2]);
      acc[v][3] = fmaf(s, m.w, acc[v][3]);
    }
  }
#pragma unroll
  for (int v = 0; v < NV; ++v)
#pragma unroll
    for (int j = 0; j < 4; ++j)
      atomicAdd(fout + (size_t)(v * 3 + l) * H + k0 + j, acc[v][j]);
}

// fp16 dot over 32 rows, 8 cols/thread; vs = NV x 32 staged vector chunks
template<int NV>
__device__ void dot16(const __half* __restrict__ Mp, const float* __restrict__ vs,
                      float* __restrict__ fout, int l, int k0) {
  float acc[NV][8];
#pragma unroll
  for (int v = 0; v < NV; ++v)
#pragma unroll
    for (int j = 0; j < 8; ++j) acc[v][j] = 0.0f;

#pragma unroll 4
  for (int hh = 0; hh < 32; ++hh) {
    union { uint4 u; __half2 h2[4]; } cv;
    cv.u = *reinterpret_cast<const uint4*>(Mp + (size_t)hh * H);
    float fr[8];
#pragma unroll
    for (int j = 0; j < 4; ++j) {
      float2 t = __half22float2(cv.h2[j]);
      fr[2 * j] = t.x; fr[2 * j + 1] = t.y;
    }
#pragma unroll
    for (int v = 0; v < NV; ++v) {
      const float s = vs[v * 32 + hh];
#pragma unroll
      for (int j = 0; j < 8; ++j) acc[v][j] = fmaf(s, fr[j], acc[v][j]);
    }
  }
#pragma unroll
  for (int v = 0; v < NV; ++v)
#pragma unroll
    for (int j = 0; j < 8; ++j)
      atomicAdd(fout + (size_t)(v * 3 + l) * H + k0 + j, acc[v][j]);
}

__global__ __launch_bounds__(256, 3) void mega_k(
    const float* __restrict__ x, const float* __restrict__ hp,
    const float* __restrict__ L, const float* __restrict__ R,
    const float* __restrict__ bias, const float* __restrict__ Ws,
    float* __restrict__ dout, __half* __restrict__ L16,
    __half* __restrict__ R16, float* __restrict__ f, int* __restrict__ bar) {
  __shared__ float smem[256];
  const int b = blockIdx.x;
  const int tid = threadIdx.x;
  float* sc = f + 30 * H;

  // P0: zero atomic accumulators (slots 0..30)
  for (int i = b * 256 + tid; i < 31 * H; i += 768 * 256) f[i] = 0.0f;
  gridbar(bar);

  // P1: xL,hL from L (v0=x, v1=h_prev); hR from R (v0=h_prev); fp16 convert
  if (b < 384) phase_gemv32<2>(L, x, hp, f, L16, b, smem);
  else         phase_gemv32<1>(R, hp, nullptr, f + 6 * H, R16, b - 384, smem);
  gridbar(bar);

  // P3: rR,z1R from R16; r,z1 recomputed in prologue from xL/hR slots
  {
    const int hc = b & 127, kt = (b >> 7) & 1, l = b >> 8;
    const int h0 = hc * 32, k0 = kt * 2048 + tid * 8;
    if (tid < 32) {
      int row = h0 + tid;
      smem[tid]      = sigmoidf_(f[1 * H + row] + f[7 * H + row] + bias[H + row]); // r
      smem[32 + tid] = sigmoidf_(f[0 * H + row] + f[6 * H + row] + bias[row]);     // z1
    }
    __syncthreads();
    dot16<2>(R16 + ((size_t)l * H + h0) * H + k0, smem, f + 9 * H, l, k0);
  }
  gridbar(bar);

  // P4: cs2 — rh/omz/z2h candidates + 12 score partials
  if (b < 16) {
    const int h = b * 256 + tid;
    const float hpv = hp[h];
    const float z3 = sigmoidf_(f[0 * H + h] + f[6 * H + h] + bias[h]);
    const float r3 = sigmoidf_(f[1 * H + h] + f[7 * H + h] + bias[H + h]);
    const float ws = Ws[h];
    float vals[12];
#pragma unroll
    for (int l = 0; l < 3; ++l) {
      const float hl = f[(3 + l) * H + h], rr = f[(9 + l) * H + h],
                  zz = f[(12 + l) * H + h];
      const float bl = bias[(size_t)l * H + h];
      float crh = fmaf(hl, rr, bl), com = 1.0f - (zz + bl), cz2 = fmaf(hl, zz, bl);
      f[(size_t)(31 + l) * H + h] = crh;
      f[(size_t)(35 + l) * H + h] = com;
      f[(size_t)(39 + l) * H + h] = cz2;
      vals[l] = crh * ws; vals[4 + l] = com * ws; vals[8 + l] = cz2 * ws;
    }
    {
      const float bl = bias[(size_t)3 * H + h];
      float crh = fmaf(hpv, r3, bl), com = 1.0f - (z3 + bl), cz2 = fmaf(hpv, z3, bl);
      f[(size_t)34 * H + h] = crh;
      f[(size_t)38 * H + h] = com;
      f[(size_t)42 * H + h] = cz2;
      vals[3] = crh * ws; vals[7] = com * ws; vals[11] = cz2 * ws;
    }
    reduce_atomic<12>(vals, sc, tid);
  }
  gridbar(bar);

  // P5: rhR,omzR,z2hR from R16, vectors = softmax mixes of cands (sc 0..11)
  {
    const int hc = b & 127, kt = (b >> 7) & 1, l = b >> 8;
    const int h0 = hc * 32, k0 = kt * 2048 + tid * 8;
    const bool storeblk = (l == 0 && kt == 0);
    if (tid < 32) {
      int row = h0 + tid;
#pragma unroll
      for (int v = 0; v < 3; ++v) {
        float w[4]; soft4(sc + v * 4, w);
        const float* cb = f + (size_t)(31 + v * 4) * H + row;
        float m = w[0] * cb[0] + w[1] * cb[H] + w[2] * cb[2 * H] + w[3] * cb[3 * H];
        smem[v * 32 + tid] = m;
        if (storeblk) f[(size_t)(57 + v) * H + row] = m;
      }
    }
    if (storeblk && hc == 0 && tid == 0) {
      idxmargin(sc + 0, dout, 0);
      idxmargin(sc + 4, dout, 2);
      idxmargin(sc + 8, dout, 4);
    }
    __syncthreads();
    dot16<3>(R16 + ((size_t)l * H + h0) * H + k0, smem, f + 15 * H, l, k0);
  }
  gridbar(bar);

  // P6: h_tilde cands = tanh(xL + rhR + b)
  if (b < 16) {
    const int h = b * 256 + tid;
    const float ws = Ws[h];
    float vals[4];
#pragma unroll
    for (int l = 0; l < 4; ++l) {
      const float a  = (l < 3) ? f[(size_t)l * H + h] : x[h];
      const float bv = (l < 3) ? f[(size_t)(15 + l) * H + h] : f[(size_t)57 * H + h];
      const float bl = bias[(size_t)l * H + h];
      float c = tanhf(a + bv + bl);
      f[(size_t)(43 + l) * H + h] = c;
      vals[l] = c * ws;
    }
    reduce_atomic<4>(vals, sc + 12, tid);
  }
  gridbar(bar);

  // P7: htL from L16, vector = mix(ht cands, sc+12)
  {
    const int hc = b & 127, kt = (b >> 7) & 1, l = b >> 8;
    const int h0 = hc * 32, k0 = kt * 2048 + tid * 8;
    const bool storeblk = (l == 0 && kt == 0);
    if (tid < 32) {
      int row = h0 + tid;
      float w[4]; soft4(sc + 12, w);
      const float* cb = f + (size_t)43 * H + row;
      float m = w[0] * cb[0] + w[1] * cb[H] + w[2] * cb[2 * H] + w[3] * cb[3 * H];
      smem[tid] = m;
      if (storeblk) f[(size_t)60 * H + row] = m;
    }
    if (storeblk && hc == 0 && tid == 0) idxmargin(sc + 12, dout, 1);
    __syncthreads();
    dot16<1>(L16 + ((size_t)l * H + h0) * H + k0, smem, f + 24 * H, l, k0);
  }
  gridbar(bar);

  // P8: zh cands = htL * omzR + b
  if (b < 16) {
    const int h = b * 256 + tid;
    const float ws = Ws[h];
    float vals[4];
#pragma unroll
    for (int l = 0; l < 4; ++l) {
      const float a  = (l < 3) ? f[(size_t)(24 + l) * H + h] : f[(size_t)60 * H + h];
      const float bv = (l < 3) ? f[(size_t)(18 + l) * H + h] : f[(size_t)58 * H + h];
      const float bl = bias[(size_t)l * H + h];
      float c = fmaf(a, bv, bl);
      f[(size_t)(47 + l) * H + h] = c;
      vals[l] = c * ws;
    }
    reduce_atomic<4>(vals, sc + 16, tid);
  }
  gridbar(bar);

  // P9: zhL from L16, vector = mix(zh cands, sc+16)
  {
    const int hc = b & 127, kt = (b >> 7) & 1, l = b >> 8;
    const int h0 = hc * 32, k0 = kt * 2048 + tid * 8;
    const bool storeblk = (l == 0 && kt == 0);
    if (tid < 32) {
      int row = h0 + tid;
      float w[4]; soft4(sc + 16, w);
      const float* cb = f + (size_t)47 * H + row;
      float m = w[0] * cb[0] + w[1] * cb[H] + w[2] * cb[2 * H] + w[3] * cb[3 * H];
      smem[tid] = m;
      if (storeblk) f[(size_t)61 * H + row] = m;
    }
    if (storeblk && hc == 0 && tid == 0) idxmargin(sc + 16, dout, 3);
    __syncthreads();
    dot16<1>(L16 + ((size_t)l * H + h0) * H + k0, smem, f + 27 * H, l, k0);
  }
  gridbar(bar);

  // P10: h_next cands = zhL + z2hR + b
  if (b < 16) {
    const int h = b * 256 + tid;
    const float ws = Ws[h];
    float vals[4];
#pragma unroll
    for (int l = 0; l < 4; ++l) {
      const float a  = (l < 3) ? f[(size_t)(27 + l) * H + h] : f[(size_t)61 * H + h];
      const float bv = (l < 3) ? f[(size_t)(21 + l) * H + h] : f[(size_t)59 * H + h];
      const float bl = bias[(size_t)l * H + h];
      float c = a + bv + bl;
      f[(size_t)(51 + l) * H + h] = c;
      vals[l] = c * ws;
    }
    reduce_atomic<4>(vals, sc + 20, tid);
  }
  gridbar(bar);

  // P11: final mix -> dout[0:H], constants, idx/margin slot 5
  if (b < 16) {
    const int h = b * 256 + tid;
    float w[4]; soft4(sc + 20, w);
    const float* cb = f + (size_t)51 * H + h;
    dout[h] = w[0] * cb[0] + w[1] * cb[H] + w[2] * cb[2 * H] + w[3] * cb[3 * H];
    if (b == 0 && tid == 0) {
      dout[H + 0] = 0.f; dout[H + 1] = 1.f; dout[H + 2] = 0.f;
      idxmargin(sc + 20, dout, 5);
    }
  }
}

extern "C" void kernel_launch(void* const* d_in, const int* in_sizes, int n_in,
                              void* d_out, int out_size, void* d_ws, size_t ws_size,
                              hipStream_t stream) {
  const float* x  = (const float*)d_in[0];
  const float* hp = (const float*)d_in[1];
  const float* L  = (const float*)d_in[2];
  const float* R  = (const float*)d_in[3];
  const float* bb = (const float*)d_in[4];
  const float* Ws = (const float*)d_in[5];
  float* out = (float*)d_out;

  __half* L16 = (__half*)d_ws;
  __half* R16 = L16 + (size_t)3 * H * H;
  float*  f   = (float*)(R16 + (size_t)3 * H * H);
  int*    bar = (int*)(f + 62 * H);

  // barrier state must start at zero every call (ws is poisoned by harness)
  hipMemsetAsync(bar, 0, 256 * sizeof(int), stream);

  mega_k<<<768, 256, 0, stream>>>(x, hp, L, R, bb, Ws, out, L16, R16, f, bar);
}